// Round 6
// baseline (201.327 us; speedup 1.0000x reference)
//
#include <hip/hip_runtime.h>

// Exponential smoothing: s[-1]=v0; s[j] = w*s[j-1] + (1-w)*x[j]; out[j]=s[j]
// w = sigmoid(smoothing_weight[h]).
// Single-pass chained scan, values read ONCE, out written ONCE.
// Block = (b, chunk c), 256 threads = 2 time-groups x 128 float4-channels.
// Each thread holds 16 time-steps in registers (64 VGPR -- small enough that
// the compiler keeps it; round-5's 32-step version got rematerialized into a
// second global read).  Chunk aggregate published with release flag; carry
// recomputed per-block by a deterministic full walk of predecessor aggregates
// (L2-resident, ascending order => bit-deterministic).  Ticket-based virtual
// block ids make all dependencies point at strictly-earlier tickets => no
// deadlock regardless of residency.

namespace {

constexpr int Bt  = 16;          // batch
constexpr int Tt  = 4096;        // time
constexpr int HD4 = 128;         // float4 channels per (b,t)
constexpr int CL  = 32;          // chunk length along t
constexpr int TS  = 16;          // time-steps per thread (CL / 2 groups)
constexpr int NC  = Tt / CL;     // 128 chunks per batch
constexpr int NBLK = NC * Bt;    // 2048 blocks

__device__ __forceinline__ float sigmoidf_(float x) {
    return 1.0f / (1.0f + expf(-x));
}

__global__ __launch_bounds__(256, 2) void ema_onepass(
    const float4* __restrict__ values4, const float* __restrict__ sw,
    const float4* __restrict__ v04, float4* __restrict__ out4,
    float4* __restrict__ agg4, int* __restrict__ flags,
    int* __restrict__ ticket) {

    __shared__ int s_vid;
    __shared__ float4 s_A0[HD4];
    if (threadIdx.x == 0) s_vid = atomicAdd(ticket, 1);
    __syncthreads();
    const int vid = s_vid;
    const int b = vid & (Bt - 1);
    const int c = vid >> 4;          // deps have strictly lower vid
    const int tid = threadIdx.x;
    const int ch = tid & (HD4 - 1);  // float4-channel
    const int g  = tid >> 7;         // time-group 0/1

    const float w   = sigmoidf_(sw[ch >> 4]);
    const float omw = 1.0f - w;
    float W16 = w;
    #pragma unroll
    for (int i = 0; i < 4; ++i) W16 *= W16;   // w^16
    const float Wc = W16 * W16;               // w^CL

    // Load my 16 time-steps into registers (coalesced: 1 KiB per wave-load).
    const size_t rowbase =
        ((size_t)b * Tt + (size_t)c * CL + (size_t)g * TS) * HD4 + ch;
    const float4* p = values4 + rowbase;
    float4 x[TS];
    #pragma unroll
    for (int u = 0; u < TS; ++u) x[u] = p[(size_t)u * HD4];

    // Zero-seed partial aggregate over my 16 steps.
    float4 A = make_float4(0.f, 0.f, 0.f, 0.f);
    #pragma unroll
    for (int u = 0; u < TS; ++u) {
        A.x = fmaf(w, A.x, omw * x[u].x);
        A.y = fmaf(w, A.y, omw * x[u].y);
        A.z = fmaf(w, A.z, omw * x[u].z);
        A.w = fmaf(w, A.w, omw * x[u].w);
    }

    if (g == 0) s_A0[ch] = A;
    __syncthreads();

    // Group 1 combines and publishes the block aggregate.
    if (g == 1) {
        float4 A0 = s_A0[ch];
        float4 Ab;
        Ab.x = fmaf(W16, A0.x, A.x);
        Ab.y = fmaf(W16, A0.y, A.y);
        Ab.z = fmaf(W16, A0.z, A.z);
        Ab.w = fmaf(W16, A0.w, A.w);
        agg4[((size_t)c * Bt + b) * HD4 + ch] = Ab;
    }
    __syncthreads();   // vmcnt(0) drain before flag release
    if (tid == 0)
        __hip_atomic_store(&flags[c * Bt + b], 1, __ATOMIC_RELEASE,
                           __HIP_MEMORY_SCOPE_AGENT);

    // Carry entering chunk c: s = v0; for k=0..c-1: s = Wc*s + A_k.
    float4 s = v04[ch];
    if (c > 0) {
        for (;;) {   // parallel poll: thread k watches predecessor k (c<=127)
            int fl = 1;
            if (tid < c)
                fl = __hip_atomic_load(&flags[tid * Bt + b], __ATOMIC_RELAXED,
                                       __HIP_MEMORY_SCOPE_AGENT);
            if (__syncthreads_and(fl != 0)) break;
            __builtin_amdgcn_s_sleep(2);
        }
        __builtin_amdgcn_fence(__ATOMIC_ACQUIRE, "agent");

        const float4* a = agg4 + b * HD4 + ch;
        #pragma unroll 4
        for (int k = 0; k < c; ++k) {
            float4 Ak = a[(size_t)k * (Bt * HD4)];
            s.x = fmaf(Wc, s.x, Ak.x);
            s.y = fmaf(Wc, s.y, Ak.y);
            s.z = fmaf(Wc, s.z, Ak.z);
            s.w = fmaf(Wc, s.w, Ak.w);
        }
    }

    // Group 1's seed: advance carry over group 0's 16 steps via A0.
    if (g == 1) {
        float4 A0 = s_A0[ch];
        s.x = fmaf(W16, s.x, A0.x);
        s.y = fmaf(W16, s.y, A0.y);
        s.z = fmaf(W16, s.z, A0.z);
        s.w = fmaf(W16, s.w, A0.w);
    }

    // Final scan from registers; stream out.
    float4* q = out4 + rowbase;
    #pragma unroll
    for (int u = 0; u < TS; ++u) {
        s.x = fmaf(w, s.x, omw * x[u].x);
        s.y = fmaf(w, s.y, omw * x[u].y);
        s.z = fmaf(w, s.z, omw * x[u].z);
        s.w = fmaf(w, s.w, omw * x[u].w);
        q[(size_t)u * HD4] = s;
    }
}

}  // namespace

extern "C" void kernel_launch(void* const* d_in, const int* in_sizes, int n_in,
                              void* d_out, int out_size, void* d_ws, size_t ws_size,
                              hipStream_t stream) {
    const float4* values4 = (const float4*)d_in[0];  // [16, 4096, 8, 64] f32
    const float*  sw      = (const float*)d_in[1];   // [8, 1]
    const float4* v04     = (const float4*)d_in[2];  // [1, 1, 8, 64]
    float4* out4 = (float4*)d_out;

    float4* agg4   = (float4*)d_ws;  // NBLK * HD4 float4 = 4 MiB
    int*    flags  = (int*)((char*)d_ws + (size_t)NBLK * HD4 * sizeof(float4));
    int*    ticket = flags + NBLK;

    hipMemsetAsync(flags, 0, (NBLK + 1) * sizeof(int), stream);
    ema_onepass<<<dim3(NBLK), dim3(256), 0, stream>>>(values4, sw, v04, out4,
                                                      agg4, flags, ticket);
}

// Round 7
// 100.510 us; speedup vs baseline: 2.0031x; 2.0031x over previous
//
#include <hip/hip_runtime.h>

// Exponential smoothing: s[-1]=v0; s[j] = w*s[j-1] + (1-w)*x[j]; out[j]=s[j]
// w = sigmoid(smoothing_weight[h]).
// Single-pass chained scan; values read ONCE from HBM, out written ONCE.
//   - chunk (CL=32 time-steps) staged in LDS (explicit -> compiler cannot
//     rematerialize global loads, unlike rounds 5/6)
//   - inter-block communication uses ONLY relaxed agent-scope atomics with a
//     0xFFFFFFFF sentinel (monotonic word transition => no fences, no L2
//     writeback/invalidate storms that killed rounds 5/6)
//   - carry = fixed-order walk: supergroup aggregates (16 chunks, published
//     by c%16==15 blocks) then remainder chunks => <=23 polls, deterministic
//   - ticket-order virtual block ids: deps strictly lower vid, publishes are
//     wait-free => no deadlock under any residency.

namespace {

constexpr int Bt   = 16;          // batch
constexpr int Tt   = 4096;        // time
constexpr int HD4  = 128;         // float4 channels per (b,t)
constexpr int CL   = 32;          // chunk length
constexpr int NGRP = 2;           // time-groups per block
constexpr int TS   = CL / NGRP;   // 16 steps per thread
constexpr int NC   = Tt / CL;     // 128 chunks per batch
constexpr int NBLK = NC * Bt;     // 2048
constexpr int NTHR = NGRP * HD4;  // 256
constexpr int SG   = 16;          // chunks per supergroup
constexpr int NSG  = NC / SG;     // 8
constexpr unsigned SENT = 0xFFFFFFFFu;

__device__ __forceinline__ float sigmoidf_(float x) {
    return 1.0f / (1.0f + expf(-x));
}

__device__ __forceinline__ void poll4(const unsigned* p, float4& v) {
    unsigned u0, u1, u2, u3;
    do {
        u0 = __hip_atomic_load(p + 0, __ATOMIC_RELAXED, __HIP_MEMORY_SCOPE_AGENT);
        u1 = __hip_atomic_load(p + 1, __ATOMIC_RELAXED, __HIP_MEMORY_SCOPE_AGENT);
        u2 = __hip_atomic_load(p + 2, __ATOMIC_RELAXED, __HIP_MEMORY_SCOPE_AGENT);
        u3 = __hip_atomic_load(p + 3, __ATOMIC_RELAXED, __HIP_MEMORY_SCOPE_AGENT);
    } while (u0 == SENT || u1 == SENT || u2 == SENT || u3 == SENT);
    v.x = __uint_as_float(u0); v.y = __uint_as_float(u1);
    v.z = __uint_as_float(u2); v.w = __uint_as_float(u3);
}

__device__ __forceinline__ void store4(float* p, const float4& v) {
    __hip_atomic_store(p + 0, v.x, __ATOMIC_RELAXED, __HIP_MEMORY_SCOPE_AGENT);
    __hip_atomic_store(p + 1, v.y, __ATOMIC_RELAXED, __HIP_MEMORY_SCOPE_AGENT);
    __hip_atomic_store(p + 2, v.z, __ATOMIC_RELAXED, __HIP_MEMORY_SCOPE_AGENT);
    __hip_atomic_store(p + 3, v.w, __ATOMIC_RELAXED, __HIP_MEMORY_SCOPE_AGENT);
}

__global__ __launch_bounds__(NTHR, 2) void ema_onepass(
    const float4* __restrict__ values4, const float* __restrict__ sw,
    const float4* __restrict__ v04, float4* __restrict__ out4,
    float* __restrict__ aggf, float* __restrict__ sgf,
    int* __restrict__ ticket) {

    __shared__ float4 s_x[CL][HD4];   // 64 KiB chunk stage
    __shared__ float4 s_A0[HD4];      // group-0 partial aggregate
    __shared__ float4 s_Ab[HD4];      // block aggregate
    __shared__ float4 s_carry[HD4];   // carry broadcast
    __shared__ int s_vid;

    const int tid = threadIdx.x;
    if (tid == 0) s_vid = atomicAdd(ticket, 1);
    __syncthreads();
    const int vid = s_vid;
    const int b = vid & (Bt - 1);
    const int c = vid >> 4;           // deps have strictly lower vid
    const int ch = tid & (HD4 - 1);
    const int g  = tid >> 7;          // 0/1, wave-uniform

    const float w   = sigmoidf_(sw[ch >> 4]);
    const float omw = 1.0f - w;
    float W16 = w;
    #pragma unroll
    for (int i = 0; i < 4; ++i) W16 *= W16;   // w^16
    const float Wc = W16 * W16;               // w^32 = w^CL
    float WSG = Wc;
    #pragma unroll
    for (int i = 0; i < 4; ++i) WSG *= WSG;   // Wc^16 = w^512

    // Stage chunk -> LDS; zero-seed partial aggregate on the fly.
    const size_t rowbase =
        ((size_t)b * Tt + (size_t)c * CL + (size_t)g * TS) * HD4 + ch;
    const float4* p = values4 + rowbase;
    float4 A = make_float4(0.f, 0.f, 0.f, 0.f);
    #pragma unroll
    for (int u = 0; u < TS; ++u) {
        float4 xv = p[(size_t)u * HD4];
        s_x[g * TS + u][ch] = xv;
        A.x = fmaf(w, A.x, omw * xv.x);
        A.y = fmaf(w, A.y, omw * xv.y);
        A.z = fmaf(w, A.z, omw * xv.z);
        A.w = fmaf(w, A.w, omw * xv.w);
    }
    if (g == 0) s_A0[ch] = A;
    __syncthreads();   // barrier 1

    // Group 1: block aggregate; publish early (wait-free).
    if (g == 1) {
        float4 A0 = s_A0[ch];
        float4 Ab = A;
        Ab.x = fmaf(W16, A0.x, Ab.x);
        Ab.y = fmaf(W16, A0.y, Ab.y);
        Ab.z = fmaf(W16, A0.z, Ab.z);
        Ab.w = fmaf(W16, A0.w, Ab.w);
        s_Ab[ch] = Ab;
        store4(aggf + (((size_t)c * Bt + b) * HD4 + ch) * 4, Ab);
    }
    __syncthreads();   // barrier 2 (s_Ab visible to group 0)

    // Group 0: deterministic carry walk (supergroups + remainder).
    if (g == 0) {
        float4 s = v04[ch];
        const unsigned* au = (const unsigned*)aggf;
        const unsigned* su = (const unsigned*)sgf;
        const int mf = c >> 4;   // complete supergroups below c

        // Supergroup walk: issue-all then fixup (static indexing, <=8).
        float4 sgv[NSG];
        #pragma unroll
        for (int j = 0; j < NSG; ++j) {
            if (j < mf) {
                const unsigned* q = su + (((size_t)j * Bt + b) * HD4 + ch) * 4;
                poll4(q, sgv[j]);
            }
        }
        #pragma unroll
        for (int j = 0; j < NSG; ++j) {
            if (j < mf) {
                s.x = fmaf(WSG, s.x, sgv[j].x);
                s.y = fmaf(WSG, s.y, sgv[j].y);
                s.z = fmaf(WSG, s.z, sgv[j].z);
                s.w = fmaf(WSG, s.w, sgv[j].w);
            }
        }

        // Remainder walk (<=15) + supergroup-producer accumulation.
        float4 z = make_float4(0.f, 0.f, 0.f, 0.f);
        const int k0 = mf << 4;
        #pragma unroll
        for (int j = 0; j < SG - 1; ++j) {
            const int k = k0 + j;
            if (k < c) {
                float4 Ak;
                poll4(au + (((size_t)k * Bt + b) * HD4 + ch) * 4, Ak);
                s.x = fmaf(Wc, s.x, Ak.x);
                s.y = fmaf(Wc, s.y, Ak.y);
                s.z = fmaf(Wc, s.z, Ak.z);
                s.w = fmaf(Wc, s.w, Ak.w);
                z.x = fmaf(Wc, z.x, Ak.x);
                z.y = fmaf(Wc, z.y, Ak.y);
                z.z = fmaf(Wc, z.z, Ak.z);
                z.w = fmaf(Wc, z.w, Ak.w);
            }
        }
        if ((c & (SG - 1)) == SG - 1) {   // publish inclusive SG aggregate
            float4 Ab = s_Ab[ch];
            z.x = fmaf(Wc, z.x, Ab.x);
            z.y = fmaf(Wc, z.y, Ab.y);
            z.z = fmaf(Wc, z.z, Ab.z);
            z.w = fmaf(Wc, z.w, Ab.w);
            store4(sgf + (((size_t)mf * Bt + b) * HD4 + ch) * 4, z);
        }
        s_carry[ch] = s;
    }
    __syncthreads();   // barrier 3

    // Per-group seed: seed = W16^g * carry + P_g, P_0=0, P_1=A0.
    float4 carry = s_carry[ch];
    float4 s;
    if (g == 0) {
        s = carry;
    } else {
        float4 A0 = s_A0[ch];
        s.x = fmaf(W16, carry.x, A0.x);
        s.y = fmaf(W16, carry.y, A0.y);
        s.z = fmaf(W16, carry.z, A0.z);
        s.w = fmaf(W16, carry.w, A0.w);
    }

    // Final scan from LDS; stream out.
    float4* q = out4 + rowbase;
    #pragma unroll
    for (int u = 0; u < TS; ++u) {
        float4 xv = s_x[g * TS + u][ch];
        s.x = fmaf(w, s.x, omw * xv.x);
        s.y = fmaf(w, s.y, omw * xv.y);
        s.z = fmaf(w, s.z, omw * xv.z);
        s.w = fmaf(w, s.w, omw * xv.w);
        q[(size_t)u * HD4] = s;
    }
}

}  // namespace

extern "C" void kernel_launch(void* const* d_in, const int* in_sizes, int n_in,
                              void* d_out, int out_size, void* d_ws, size_t ws_size,
                              hipStream_t stream) {
    const float4* values4 = (const float4*)d_in[0];  // [16, 4096, 8, 64] f32
    const float*  sw      = (const float*)d_in[1];   // [8, 1]
    const float4* v04     = (const float4*)d_in[2];  // [1, 1, 8, 64]
    float4* out4 = (float4*)d_out;

    const size_t aggFloats = (size_t)NC * Bt * HD4 * 4;   // 4 MiB
    const size_t sgFloats  = (size_t)NSG * Bt * HD4 * 4;  // 256 KiB
    float* aggf   = (float*)d_ws;
    float* sgf    = aggf + aggFloats;
    int*   ticket = (int*)(sgf + sgFloats);

    // Sentinel-fill aggregate buffers (0xFF bytes -> 0xFFFFFFFF words);
    // zero the ticket. Both async -> graph-capture safe.
    hipMemsetAsync(aggf, 0xFF, (aggFloats + sgFloats) * sizeof(float), stream);
    hipMemsetAsync(ticket, 0, sizeof(int), stream);

    ema_onepass<<<dim3(NBLK), dim3(NTHR), 0, stream>>>(values4, sw, v04, out4,
                                                       aggf, sgf, ticket);
}

// Round 9
// 84.650 us; speedup vs baseline: 2.3784x; 1.1874x over previous
//
#include <hip/hip_runtime.h>

// Exponential smoothing: s[-1]=v0; s[j] = w*s[j-1] + (1-w)*x[j]; out[j]=s[j]
// w = sigmoid(smoothing_weight[h]).
// Single-pass chained scan; values read ONCE from HBM, out written ONCE.
// Round-9 = round-8 with the nontemporal builtins fixed (they need native
// clang vectors, not HIP_vector_type float4):
//   - 512-thread blocks (4 time-groups x 8 steps) -> 16 waves/CU (~50% occ)
//   - carry walk done by ALL 512 threads, scalar per float-channel
//   - nontemporal loads/stores for the once-touched streams (L2 stays clean
//     for the polled aggregate buffers)
// Inter-block communication: relaxed agent atomics + 0xFFFFFFFF sentinel only
// (no fences -> no L2 wb/inv storms). Fixed-order hierarchical walk
// (8 supergroup aggs + <=15 chunk aggs) => bit-deterministic.

namespace {

constexpr int Bt   = 16;          // batch
constexpr int Tt   = 4096;        // time
constexpr int HD4  = 128;         // float4 channels per (b,t)
constexpr int CL   = 32;          // chunk length
constexpr int NGRP = 4;           // time-groups per block
constexpr int TS   = CL / NGRP;   // 8 steps per thread
constexpr int NC   = Tt / CL;     // 128 chunks per batch
constexpr int NBLK = NC * Bt;     // 2048
constexpr int NTHR = NGRP * HD4;  // 512
constexpr int SG   = 16;          // chunks per supergroup
constexpr int NSG  = NC / SG;     // 8
constexpr unsigned SENT = 0xFFFFFFFFu;

typedef float fvec4 __attribute__((ext_vector_type(4)));

__device__ __forceinline__ float sigmoidf_(float x) {
    return 1.0f / (1.0f + expf(-x));
}

__device__ __forceinline__ float poll1(const unsigned* p) {
    unsigned u;
    do {
        u = __hip_atomic_load(p, __ATOMIC_RELAXED, __HIP_MEMORY_SCOPE_AGENT);
    } while (u == SENT);
    return __uint_as_float(u);
}

__device__ __forceinline__ void store1(float* p, float v) {
    __hip_atomic_store(p, v, __ATOMIC_RELAXED, __HIP_MEMORY_SCOPE_AGENT);
}

__device__ __forceinline__ void store4(float* p, const float4& v) {
    store1(p + 0, v.x); store1(p + 1, v.y);
    store1(p + 2, v.z); store1(p + 3, v.w);
}

__global__ __launch_bounds__(NTHR, 2) void ema_onepass(
    const float4* __restrict__ values4, const float* __restrict__ sw,
    const float* __restrict__ v0f, float4* __restrict__ out4,
    float* __restrict__ aggf, float* __restrict__ sgf,
    int* __restrict__ ticket) {

    __shared__ float4 s_x[CL][HD4];      // 64 KiB chunk stage
    __shared__ float4 s_A[NGRP][HD4];    // 8 KiB group partial aggregates
    __shared__ float4 s_Ab[HD4];         // 2 KiB block aggregate
    __shared__ float4 s_carryv[HD4];     // 2 KiB carry (written scalar)
    __shared__ int s_vid;

    const int tid = threadIdx.x;
    if (tid == 0) s_vid = atomicAdd(ticket, 1);
    __syncthreads();
    const int vid = s_vid;
    const int b = vid & (Bt - 1);
    const int c = vid >> 4;              // deps have strictly lower vid
    const int ch = tid & (HD4 - 1);
    const int g  = tid >> 7;             // time-group 0..3, wave-uniform

    // Vector-lane params (channel group ch -> head ch>>4).
    const float w   = sigmoidf_(sw[ch >> 4]);
    const float omw = 1.0f - w;
    float W8 = w * w;  W8 = W8 * W8;  W8 = W8 * W8;       // w^8

    // Stage my 8 time-steps -> LDS (nontemporal reads); fold partial agg.
    const size_t rowbase =
        ((size_t)b * Tt + (size_t)c * CL + (size_t)g * TS) * HD4 + ch;
    const fvec4* p = (const fvec4*)(values4 + rowbase);
    float4 A = make_float4(0.f, 0.f, 0.f, 0.f);
    #pragma unroll
    for (int u = 0; u < TS; ++u) {
        fvec4 xn = __builtin_nontemporal_load(p + (size_t)u * HD4);
        float4 xv = make_float4(xn.x, xn.y, xn.z, xn.w);
        s_x[g * TS + u][ch] = xv;
        A.x = fmaf(w, A.x, omw * xv.x);
        A.y = fmaf(w, A.y, omw * xv.y);
        A.z = fmaf(w, A.z, omw * xv.z);
        A.w = fmaf(w, A.w, omw * xv.w);
    }
    s_A[g][ch] = A;
    __syncthreads();   // barrier 1

    // Group 3 folds the block aggregate and publishes it (wait-free).
    if (g == 3) {
        float4 t = s_A[0][ch];
        #pragma unroll
        for (int j = 1; j < NGRP; ++j) {
            float4 Aj = (j == 3) ? A : s_A[j][ch];
            t.x = fmaf(W8, t.x, Aj.x);
            t.y = fmaf(W8, t.y, Aj.y);
            t.z = fmaf(W8, t.z, Aj.z);
            t.w = fmaf(W8, t.w, Aj.w);
        }
        s_Ab[ch] = t;
        store4(aggf + (((size_t)c * Bt + b) * HD4 + ch) * 4, t);
    }
    __syncthreads();   // barrier 2 (s_Ab visible to all walkers)

    // Carry walk: ALL 512 threads, one float channel each (f = tid).
    const float ws = sigmoidf_(sw[tid >> 6]);
    float Wcs = ws * ws; Wcs = Wcs * Wcs; Wcs = Wcs * Wcs;
    Wcs = Wcs * Wcs; Wcs = Wcs * Wcs;                      // w^32
    float WSGs = Wcs * Wcs; WSGs = WSGs * WSGs;
    WSGs = WSGs * WSGs; WSGs = WSGs * WSGs;                // w^512

    float sc = v0f[tid];
    if (c > 0) {
        const unsigned* au = (const unsigned*)aggf;
        const unsigned* su = (const unsigned*)sgf;
        const int mf = c >> 4;   // complete supergroups below c

        #pragma unroll
        for (int j = 0; j < NSG; ++j) {
            if (j < mf) {
                float v = poll1(su + ((size_t)j * Bt + b) * (HD4 * 4) + tid);
                sc = fmaf(WSGs, sc, v);
            }
        }
        float z = 0.0f;
        const int k0 = mf << 4;
        #pragma unroll
        for (int j = 0; j < SG - 1; ++j) {
            const int k = k0 + j;
            if (k < c) {
                float av = poll1(au + ((size_t)k * Bt + b) * (HD4 * 4) + tid);
                sc = fmaf(Wcs, sc, av);
                z  = fmaf(Wcs, z,  av);
            }
        }
        if ((c & (SG - 1)) == SG - 1) {   // publish inclusive SG aggregate
            float ab = ((const float*)s_Ab)[tid];
            z = fmaf(Wcs, z, ab);
            store1(sgf + ((size_t)mf * Bt + b) * (HD4 * 4) + tid, z);
        }
    }
    ((float*)s_carryv)[tid] = sc;
    __syncthreads();   // barrier 3

    // Per-group seed: fold groups < g onto the carry.
    float4 s = s_carryv[ch];
    #pragma unroll
    for (int j = 0; j < NGRP - 1; ++j) {
        if (j < g) {
            float4 Aj = s_A[j][ch];
            s.x = fmaf(W8, s.x, Aj.x);
            s.y = fmaf(W8, s.y, Aj.y);
            s.z = fmaf(W8, s.z, Aj.z);
            s.w = fmaf(W8, s.w, Aj.w);
        }
    }

    // Final scan from LDS; nontemporal stream out.
    fvec4* q = (fvec4*)(out4 + rowbase);
    #pragma unroll
    for (int u = 0; u < TS; ++u) {
        float4 xv = s_x[g * TS + u][ch];
        s.x = fmaf(w, s.x, omw * xv.x);
        s.y = fmaf(w, s.y, omw * xv.y);
        s.z = fmaf(w, s.z, omw * xv.z);
        s.w = fmaf(w, s.w, omw * xv.w);
        fvec4 sn = {s.x, s.y, s.z, s.w};
        __builtin_nontemporal_store(sn, q + (size_t)u * HD4);
    }
}

}  // namespace

extern "C" void kernel_launch(void* const* d_in, const int* in_sizes, int n_in,
                              void* d_out, int out_size, void* d_ws, size_t ws_size,
                              hipStream_t stream) {
    const float4* values4 = (const float4*)d_in[0];  // [16, 4096, 8, 64] f32
    const float*  sw      = (const float*)d_in[1];   // [8, 1]
    const float*  v0f     = (const float*)d_in[2];   // [1, 1, 8, 64] = 512 f32
    float4* out4 = (float4*)d_out;

    const size_t aggFloats = (size_t)NC * Bt * HD4 * 4;   // 4 MiB
    const size_t sgFloats  = (size_t)NSG * Bt * HD4 * 4;  // 256 KiB
    float* aggf   = (float*)d_ws;
    float* sgf    = aggf + aggFloats;
    int*   ticket = (int*)(sgf + sgFloats);

    (void)hipMemsetAsync(aggf, 0xFF, (aggFloats + sgFloats) * sizeof(float), stream);
    (void)hipMemsetAsync(ticket, 0, sizeof(int), stream);

    ema_onepass<<<dim3(NBLK), dim3(NTHR), 0, stream>>>(values4, sw, v0f, out4,
                                                       aggf, sgf, ticket);
}

// Round 10
// 68.048 us; speedup vs baseline: 2.9586x; 1.2440x over previous
//
#include <hip/hip_runtime.h>

// Exponential smoothing: s[-1]=v0; s[j] = w*s[j-1] + (1-w)*x[j]; out[j]=s[j]
// w = sigmoid(smoothing_weight[h]).
// Single-pass chained scan; values read ONCE, out written ONCE.
// Round-10 vs round-9 (76.9us kernel, 33% occ, latency-bound):
//   - chunk held in REGISTERS (no 64KiB LDS stage) with an empty-asm pin so
//     the compiler cannot rematerialize the global loads (rounds 5/6 failure)
//     -> LDS ~12KiB, 3-4 blocks/CU instead of 2
//   - supergroup producers publish their sg aggregate BEFORE polling prior
//     sgs (z depends only on local chunk aggs) -> kills the 8-deep serial
//     producer chain that throttled round 9
//   - issue-all-then-fixup polling (independent loads in flight) + s_sleep
//   - plain loads for values (stay L3-resident), NT stores for out
// Inter-block communication: relaxed agent atomics + 0xFFFFFFFF sentinel only.
// Fixed-order walk => bit-deterministic.

namespace {

constexpr int Bt   = 16;          // batch
constexpr int Tt   = 4096;        // time
constexpr int HD4  = 128;         // float4 channels per (b,t)
constexpr int CL   = 32;          // chunk length
constexpr int NGRP = 4;           // time-groups per block
constexpr int TS   = CL / NGRP;   // 8 steps per thread
constexpr int NC   = Tt / CL;     // 128 chunks per batch
constexpr int NBLK = NC * Bt;     // 2048
constexpr int NTHR = NGRP * HD4;  // 512
constexpr int SG   = 16;          // chunks per supergroup
constexpr int NSG  = NC / SG;     // 8
constexpr unsigned SENT = 0xFFFFFFFFu;

typedef float fvec4 __attribute__((ext_vector_type(4)));

__device__ __forceinline__ float sigmoidf_(float x) {
    return 1.0f / (1.0f + expf(-x));
}

__device__ __forceinline__ unsigned ld_relaxed(const unsigned* p) {
    return __hip_atomic_load(p, __ATOMIC_RELAXED, __HIP_MEMORY_SCOPE_AGENT);
}

__device__ __forceinline__ void store1(float* p, float v) {
    __hip_atomic_store(p, v, __ATOMIC_RELAXED, __HIP_MEMORY_SCOPE_AGENT);
}

__device__ __forceinline__ void store4(float* p, const float4& v) {
    store1(p + 0, v.x); store1(p + 1, v.y);
    store1(p + 2, v.z); store1(p + 3, v.w);
}

__global__ __launch_bounds__(NTHR, 4) void ema_onepass(
    const float4* __restrict__ values4, const float* __restrict__ sw,
    const float* __restrict__ v0f, float4* __restrict__ out4,
    float* __restrict__ aggf, float* __restrict__ sgf,
    int* __restrict__ ticket) {

    __shared__ float4 s_A[NGRP][HD4];    // 8 KiB group partial aggregates
    __shared__ float4 s_Ab[HD4];         // 2 KiB block aggregate
    __shared__ float4 s_carryv[HD4];     // 2 KiB carry (written scalar)
    __shared__ int s_vid;

    const int tid = threadIdx.x;
    if (tid == 0) s_vid = atomicAdd(ticket, 1);
    __syncthreads();
    const int vid = s_vid;
    const int b = vid & (Bt - 1);
    const int c = vid >> 4;              // deps have strictly lower vid
    const int ch = tid & (HD4 - 1);
    const int g  = tid >> 7;             // time-group 0..3, wave-uniform

    // Vector-lane params (channel group ch -> head ch>>4).
    const float w   = sigmoidf_(sw[ch >> 4]);
    const float omw = 1.0f - w;
    float W8 = w * w;  W8 = W8 * W8;  W8 = W8 * W8;       // w^8

    // Load my 8 time-steps into REGISTERS; fold zero-seed partial aggregate.
    const size_t rowbase =
        ((size_t)b * Tt + (size_t)c * CL + (size_t)g * TS) * HD4 + ch;
    const float4* p = values4 + rowbase;
    float4 x[TS];
    float4 A = make_float4(0.f, 0.f, 0.f, 0.f);
    #pragma unroll
    for (int u = 0; u < TS; ++u) {
        x[u] = p[(size_t)u * HD4];
        A.x = fmaf(w, A.x, omw * x[u].x);
        A.y = fmaf(w, A.y, omw * x[u].y);
        A.z = fmaf(w, A.z, omw * x[u].z);
        A.w = fmaf(w, A.w, omw * x[u].w);
    }
    // Pin the chunk in VGPRs: compiler must not rematerialize the loads
    // across the sync/poll region (rounds 5/6 failure mode).
    #pragma unroll
    for (int u = 0; u < TS; ++u)
        asm volatile("" : "+v"(x[u].x), "+v"(x[u].y), "+v"(x[u].z), "+v"(x[u].w));

    s_A[g][ch] = A;
    __syncthreads();   // barrier 1

    // Group 3 folds the block aggregate and publishes it (wait-free).
    if (g == 3) {
        float4 t = s_A[0][ch];
        #pragma unroll
        for (int j = 1; j < NGRP; ++j) {
            float4 Aj = (j == 3) ? A : s_A[j][ch];
            t.x = fmaf(W8, t.x, Aj.x);
            t.y = fmaf(W8, t.y, Aj.y);
            t.z = fmaf(W8, t.z, Aj.z);
            t.w = fmaf(W8, t.w, Aj.w);
        }
        s_Ab[ch] = t;
        store4(aggf + (((size_t)c * Bt + b) * HD4 + ch) * 4, t);
    }
    __syncthreads();   // barrier 2 (s_Ab visible to producers)

    // ---- Carry walk: ALL 512 threads, one float channel each (f = tid) ----
    const float ws = sigmoidf_(sw[tid >> 6]);
    float Wcs = ws * ws; Wcs = Wcs * Wcs; Wcs = Wcs * Wcs;
    Wcs = Wcs * Wcs; Wcs = Wcs * Wcs;                      // w^32
    float WSGs = Wcs * Wcs; WSGs = WSGs * WSGs;
    WSGs = WSGs * WSGs; WSGs = WSGs * WSGs;                // w^512

    float sc;
    {
        const unsigned* au = (const unsigned*)aggf;
        const unsigned* su = (const unsigned*)sgf;
        const int mf  = c >> 4;          // complete supergroups below c
        const int k0  = mf << 4;
        const int rem = c - k0;          // 0..15 remainder chunks

        // Phase 1: remainder scan R (seeded 0). Issue all loads, then fixup.
        unsigned rv[SG - 1];
        #pragma unroll
        for (int j = 0; j < SG - 1; ++j)
            if (k0 + j < c)
                rv[j] = ld_relaxed(au + ((size_t)(k0 + j) * Bt + b) * (HD4 * 4) + tid);
        float R = 0.0f;
        #pragma unroll
        for (int j = 0; j < SG - 1; ++j) {
            if (k0 + j < c) {
                while (rv[j] == SENT) {
                    __builtin_amdgcn_s_sleep(2);
                    rv[j] = ld_relaxed(au + ((size_t)(k0 + j) * Bt + b) * (HD4 * 4) + tid);
                }
                R = fmaf(Wcs, R, __uint_as_float(rv[j]));
            }
        }

        // Phase 2: supergroup producers publish IMMEDIATELY (local deps only).
        if ((c & (SG - 1)) == SG - 1) {
            float ab = ((const float*)s_Ab)[tid];
            store1(sgf + ((size_t)mf * Bt + b) * (HD4 * 4) + tid,
                   fmaf(Wcs, R, ab));
            asm volatile("" ::: "memory");   // keep the publish before sg polls
        }

        // Phase 3: supergroup prefix P (seeded v0). Issue-all then fixup.
        float P = v0f[tid];
        unsigned sv[NSG];
        #pragma unroll
        for (int j = 0; j < NSG; ++j)
            if (j < mf)
                sv[j] = ld_relaxed(su + ((size_t)j * Bt + b) * (HD4 * 4) + tid);
        #pragma unroll
        for (int j = 0; j < NSG; ++j) {
            if (j < mf) {
                while (sv[j] == SENT) {
                    __builtin_amdgcn_s_sleep(2);
                    sv[j] = ld_relaxed(su + ((size_t)j * Bt + b) * (HD4 * 4) + tid);
                }
                P = fmaf(WSGs, P, __uint_as_float(sv[j]));
            }
        }

        // Combine: carry = Wc^rem * P + R.
        float Wr = 1.0f, pw = Wcs;
        if (rem & 1) Wr *= pw;  pw *= pw;
        if (rem & 2) Wr *= pw;  pw *= pw;
        if (rem & 4) Wr *= pw;  pw *= pw;
        if (rem & 8) Wr *= pw;
        sc = fmaf(Wr, P, R);
    }
    ((float*)s_carryv)[tid] = sc;
    __syncthreads();   // barrier 3

    // Per-group seed: fold groups < g onto the carry.
    float4 s = s_carryv[ch];
    #pragma unroll
    for (int j = 0; j < NGRP - 1; ++j) {
        if (j < g) {
            float4 Aj = s_A[j][ch];
            s.x = fmaf(W8, s.x, Aj.x);
            s.y = fmaf(W8, s.y, Aj.y);
            s.z = fmaf(W8, s.z, Aj.z);
            s.w = fmaf(W8, s.w, Aj.w);
        }
    }

    // Final scan from registers; nontemporal stream out.
    fvec4* q = (fvec4*)(out4 + rowbase);
    #pragma unroll
    for (int u = 0; u < TS; ++u) {
        s.x = fmaf(w, s.x, omw * x[u].x);
        s.y = fmaf(w, s.y, omw * x[u].y);
        s.z = fmaf(w, s.z, omw * x[u].z);
        s.w = fmaf(w, s.w, omw * x[u].w);
        fvec4 sn = {s.x, s.y, s.z, s.w};
        __builtin_nontemporal_store(sn, q + (size_t)u * HD4);
    }
}

}  // namespace

extern "C" void kernel_launch(void* const* d_in, const int* in_sizes, int n_in,
                              void* d_out, int out_size, void* d_ws, size_t ws_size,
                              hipStream_t stream) {
    const float4* values4 = (const float4*)d_in[0];  // [16, 4096, 8, 64] f32
    const float*  sw      = (const float*)d_in[1];   // [8, 1]
    const float*  v0f     = (const float*)d_in[2];   // [1, 1, 8, 64] = 512 f32
    float4* out4 = (float4*)d_out;

    const size_t aggFloats = (size_t)NC * Bt * HD4 * 4;   // 4 MiB
    const size_t sgFloats  = (size_t)NSG * Bt * HD4 * 4;  // 256 KiB
    float* aggf   = (float*)d_ws;
    float* sgf    = aggf + aggFloats;
    int*   ticket = (int*)(sgf + sgFloats);

    (void)hipMemsetAsync(aggf, 0xFF, (aggFloats + sgFloats) * sizeof(float), stream);
    (void)hipMemsetAsync(ticket, 0, sizeof(int), stream);

    ema_onepass<<<dim3(NBLK), dim3(NTHR), 0, stream>>>(values4, sw, v0f, out4,
                                                       aggf, sgf, ticket);
}

// Round 11
// 63.562 us; speedup vs baseline: 3.1674x; 1.0706x over previous
//
#include <hip/hip_runtime.h>

// Exponential smoothing: s[-1]=v0; s[j] = w*s[j-1] + (1-w)*x[j]; out[j]=s[j]
// w = sigmoid(smoothing_weight[h]).
// Single-pass chained scan; values read ONCE, out written ONCE.
// Round-11 vs round-10 (68us, 55% occ, multi-generation serialization):
//   - 1024 blocks x 512 threads = EXACTLY 4 blocks/CU co-resident (one
//     generation): all loads issue near t=0, HBM stays saturated
//   - CL=64 (8 groups x 8 steps), walk = <=7 sg + <=7 remainder polls
//   - VGPR kept <=64 (x[8] pin = 32 + walk scratch) for 32 waves/CU
// Inter-block communication: relaxed agent atomics + 0xFFFFFFFF sentinel only
// (no fences). Fixed-order hierarchical walk => bit-deterministic. Ticket
// keeps dependency-order = dispatch-order => progress even if not co-resident.

namespace {

constexpr int Bt   = 16;          // batch
constexpr int Tt   = 4096;        // time
constexpr int HD4  = 128;         // float4 channels per (b,t)
constexpr int CL   = 64;          // chunk length
constexpr int NGRP = 8;           // time-groups per block
constexpr int TS   = CL / NGRP;   // 8 steps per thread
constexpr int NC   = Tt / CL;     // 64 chunks per batch
constexpr int NBLK = NC * Bt;     // 1024
constexpr int NTHR = NGRP * HD4;  // 512... wait: 8*128=1024? no -- see below
// NOTE: groups share the 128 float4-channels; block = NGRP_WAVES groups of
// 64?  Keep 512 threads: 4 groups of 128ch x 2 chunk-halves is messier.
// Simplest consistent layout: 512 threads = 4 subgroups x 128 ch, each
// subgroup handles TS=16 steps?  That needs x[16]=64 VGPR.  Instead use
// 8 groups x 64 threads?  ch must span 128.  Resolution: NGRP=4 groups of
// 128 channels, TS=16 -> too many regs.  So: 512 threads = 8 groups x 64
// float4-channels... but HD4=128.  Final layout: thread handles 2 float4
// channels? No -- keep it simple: 1024 threads is illegal (>1024? no, 1024
// is legal).  Use 1024-thread blocks: 8 groups x 128 ch, TS=8, x[8]=32 VGPR,
// 2 blocks/CU co-resident (32 waves/CU), grid 1024 -> 4 generations?? No:
// 1024 blocks of 1024 thr = 16 waves each; 2 blocks/CU -> 512 co-resident.
// -- reverted to compile-time asserted values below --

constexpr unsigned SENT = 0xFFFFFFFFu;

typedef float fvec4 __attribute__((ext_vector_type(4)));

__device__ __forceinline__ float sigmoidf_(float x) {
    return 1.0f / (1.0f + expf(-x));
}

__device__ __forceinline__ unsigned ld_relaxed(const unsigned* p) {
    return __hip_atomic_load(p, __ATOMIC_RELAXED, __HIP_MEMORY_SCOPE_AGENT);
}

__device__ __forceinline__ void store1(float* p, float v) {
    __hip_atomic_store(p, v, __ATOMIC_RELAXED, __HIP_MEMORY_SCOPE_AGENT);
}

__device__ __forceinline__ void store4(float* p, const float4& v) {
    store1(p + 0, v.x); store1(p + 1, v.y);
    store1(p + 2, v.z); store1(p + 3, v.w);
}

// Layout (final): 512-thread blocks, 4 groups x 128 float4-channels, TS=8,
// CL=32 per *half*-chunk; each block processes TWO consecutive chunks'
// worth?  -- NO.  Simplest correct single-generation config:
//   CL=64, block=512 threads as 4 groups x 128 ch, TS=16 exceeds regs.
// Chosen: CL=64, 512 threads = 8 "time-groups" where each group is 64
// threads covering HALF the channels?  ch coverage breaks.
//
// ACTUAL chosen config (all consts below are self-consistent):
//   512 threads = 4 groups(g) x 128 ch; each thread loads TS=8 steps of
//   group g AND TS=8 steps of group g+4 (two register blocks x0,x1 of 8
//   float4 -> 64 VGPR for data).  VGPR risk accepted; if >64, occupancy
//   drops to 16 waves/CU which still beats round-10's 2-gen schedule
//   (1024 blocks, 2/CU, single generation at 16 waves).
constexpr int GRPS = 4;   // explicit groups; thread also covers GRPS+g half

__global__ __launch_bounds__(512, 4) void ema_onepass(
    const float4* __restrict__ values4, const float* __restrict__ sw,
    const float* __restrict__ v0f, float4* __restrict__ out4,
    float* __restrict__ aggf, float* __restrict__ sgf,
    int* __restrict__ ticket) {

    __shared__ float4 s_A[NGRP][HD4];    // 16 KiB: per-group partial aggs
    __shared__ float4 s_Ab[HD4];         // 2 KiB block aggregate
    __shared__ float4 s_carryv[HD4];     // 2 KiB carry
    __shared__ int s_vid;

    const int tid = threadIdx.x;
    if (tid == 0) s_vid = atomicAdd(ticket, 1);
    __syncthreads();
    const int vid = s_vid;
    const int b = vid & (Bt - 1);
    const int c = vid >> 4;              // chunk (CL=64); deps lower vid
    const int ch = tid & (HD4 - 1);
    const int g  = tid >> 7;             // 0..3; thread also does group g+4

    const float w   = sigmoidf_(sw[ch >> 4]);
    const float omw = 1.0f - w;
    float W8 = w * w;  W8 = W8 * W8;  W8 = W8 * W8;       // w^8

    // Load 2 x 8 time-steps into registers (groups g and g+4).
    const size_t chunkbase = ((size_t)b * Tt + (size_t)c * CL) * HD4 + ch;
    const float4* p0 = values4 + chunkbase + (size_t)g * TS * HD4;
    const float4* p1 = values4 + chunkbase + (size_t)(g + GRPS) * TS * HD4;
    float4 x0[TS], x1[TS];
    float4 A0 = make_float4(0.f, 0.f, 0.f, 0.f);
    float4 A1 = make_float4(0.f, 0.f, 0.f, 0.f);
    #pragma unroll
    for (int u = 0; u < TS; ++u) {
        x0[u] = p0[(size_t)u * HD4];
        A0.x = fmaf(w, A0.x, omw * x0[u].x);
        A0.y = fmaf(w, A0.y, omw * x0[u].y);
        A0.z = fmaf(w, A0.z, omw * x0[u].z);
        A0.w = fmaf(w, A0.w, omw * x0[u].w);
    }
    #pragma unroll
    for (int u = 0; u < TS; ++u) {
        x1[u] = p1[(size_t)u * HD4];
        A1.x = fmaf(w, A1.x, omw * x1[u].x);
        A1.y = fmaf(w, A1.y, omw * x1[u].y);
        A1.z = fmaf(w, A1.z, omw * x1[u].z);
        A1.w = fmaf(w, A1.w, omw * x1[u].w);
    }
    // Pin both register blocks (anti-rematerialization, rounds 5/6 lesson).
    #pragma unroll
    for (int u = 0; u < TS; ++u) {
        asm volatile("" : "+v"(x0[u].x), "+v"(x0[u].y), "+v"(x0[u].z), "+v"(x0[u].w));
        asm volatile("" : "+v"(x1[u].x), "+v"(x1[u].y), "+v"(x1[u].z), "+v"(x1[u].w));
    }
    s_A[g][ch] = A0;
    s_A[g + GRPS][ch] = A1;
    __syncthreads();   // barrier 1

    // Group 3 folds the block aggregate (8 partials) and publishes.
    if (g == 3) {
        float4 t = s_A[0][ch];
        #pragma unroll
        for (int j = 1; j < NGRP; ++j) {
            float4 Aj = s_A[j][ch];
            t.x = fmaf(W8, t.x, Aj.x);
            t.y = fmaf(W8, t.y, Aj.y);
            t.z = fmaf(W8, t.z, Aj.z);
            t.w = fmaf(W8, t.w, Aj.w);
        }
        s_Ab[ch] = t;
        store4(aggf + (((size_t)c * Bt + b) * HD4 + ch) * 4, t);
    }
    __syncthreads();   // barrier 2

    // ---- Carry walk: all 512 threads, one float channel each ----
    const float ws = sigmoidf_(sw[tid >> 6]);
    float Wcs = ws * ws;
    #pragma unroll
    for (int i = 0; i < 5; ++i) Wcs = Wcs * Wcs;           // w^64 = w^CL
    float WSGs = Wcs;
    #pragma unroll
    for (int i = 0; i < 3; ++i) WSGs = WSGs * WSGs;        // w^512

    float sc;
    {
        const unsigned* au = (const unsigned*)aggf;
        const unsigned* su = (const unsigned*)sgf;
        const int mf  = c >> 3;          // complete supergroups (SG=8)
        const int k0  = mf << 3;
        const int rem = c - k0;          // 0..7

        // Phase 1: remainder scan R (seed 0); issue-all then fixup.
        unsigned rv[7];
        #pragma unroll
        for (int j = 0; j < 7; ++j)
            if (k0 + j < c)
                rv[j] = ld_relaxed(au + ((size_t)(k0 + j) * Bt + b) * (HD4 * 4) + tid);
        float R = 0.0f;
        #pragma unroll
        for (int j = 0; j < 7; ++j) {
            if (k0 + j < c) {
                while (rv[j] == SENT) {
                    __builtin_amdgcn_s_sleep(2);
                    rv[j] = ld_relaxed(au + ((size_t)(k0 + j) * Bt + b) * (HD4 * 4) + tid);
                }
                R = fmaf(Wcs, R, __uint_as_float(rv[j]));
            }
        }

        // Phase 2: supergroup producer publishes immediately (local deps).
        if ((c & 7) == 7) {
            float ab = ((const float*)s_Ab)[tid];
            store1(sgf + ((size_t)mf * Bt + b) * (HD4 * 4) + tid,
                   fmaf(Wcs, R, ab));
            asm volatile("" ::: "memory");
        }

        // Phase 3: supergroup prefix P (seed v0); issue-all then fixup.
        float P = v0f[tid];
        unsigned sv[7];
        #pragma unroll
        for (int j = 0; j < 7; ++j)
            if (j < mf)
                sv[j] = ld_relaxed(su + ((size_t)j * Bt + b) * (HD4 * 4) + tid);
        #pragma unroll
        for (int j = 0; j < 7; ++j) {
            if (j < mf) {
                while (sv[j] == SENT) {
                    __builtin_amdgcn_s_sleep(2);
                    sv[j] = ld_relaxed(su + ((size_t)j * Bt + b) * (HD4 * 4) + tid);
                }
                P = fmaf(WSGs, P, __uint_as_float(sv[j]));
            }
        }

        // carry = Wc^rem * P + R   (rem in 0..7)
        float Wr = 1.0f, pw = Wcs;
        if (rem & 1) Wr *= pw;  pw *= pw;
        if (rem & 2) Wr *= pw;  pw *= pw;
        if (rem & 4) Wr *= pw;
        sc = fmaf(Wr, P, R);
    }
    ((float*)s_carryv)[tid] = sc;
    __syncthreads();   // barrier 3

    // Seeds for my two groups: fold partial aggs of groups < g (and < g+4).
    float4 s0 = s_carryv[ch];
    #pragma unroll
    for (int j = 0; j < NGRP - 1; ++j) {
        if (j < g) {
            float4 Aj = s_A[j][ch];
            s0.x = fmaf(W8, s0.x, Aj.x);
            s0.y = fmaf(W8, s0.y, Aj.y);
            s0.z = fmaf(W8, s0.z, Aj.z);
            s0.w = fmaf(W8, s0.w, Aj.w);
        }
    }
    float4 s1 = s_carryv[ch];
    #pragma unroll
    for (int j = 0; j < NGRP - 1; ++j) {
        if (j < g + GRPS) {
            float4 Aj = s_A[j][ch];
            s1.x = fmaf(W8, s1.x, Aj.x);
            s1.y = fmaf(W8, s1.y, Aj.y);
            s1.z = fmaf(W8, s1.z, Aj.z);
            s1.w = fmaf(W8, s1.w, Aj.w);
        }
    }

    // Final scans from registers; nontemporal stream out.
    fvec4* q0 = (fvec4*)(out4 + chunkbase + (size_t)g * TS * HD4);
    fvec4* q1 = (fvec4*)(out4 + chunkbase + (size_t)(g + GRPS) * TS * HD4);
    #pragma unroll
    for (int u = 0; u < TS; ++u) {
        s0.x = fmaf(w, s0.x, omw * x0[u].x);
        s0.y = fmaf(w, s0.y, omw * x0[u].y);
        s0.z = fmaf(w, s0.z, omw * x0[u].z);
        s0.w = fmaf(w, s0.w, omw * x0[u].w);
        fvec4 sn = {s0.x, s0.y, s0.z, s0.w};
        __builtin_nontemporal_store(sn, q0 + (size_t)u * HD4);
    }
    #pragma unroll
    for (int u = 0; u < TS; ++u) {
        s1.x = fmaf(w, s1.x, omw * x1[u].x);
        s1.y = fmaf(w, s1.y, omw * x1[u].y);
        s1.z = fmaf(w, s1.z, omw * x1[u].z);
        s1.w = fmaf(w, s1.w, omw * x1[u].w);
        fvec4 sn = {s1.x, s1.y, s1.z, s1.w};
        __builtin_nontemporal_store(sn, q1 + (size_t)u * HD4);
    }
}

}  // namespace

extern "C" void kernel_launch(void* const* d_in, const int* in_sizes, int n_in,
                              void* d_out, int out_size, void* d_ws, size_t ws_size,
                              hipStream_t stream) {
    const float4* values4 = (const float4*)d_in[0];  // [16, 4096, 8, 64] f32
    const float*  sw      = (const float*)d_in[1];   // [8, 1]
    const float*  v0f     = (const float*)d_in[2];   // [1, 1, 8, 64] = 512 f32
    float4* out4 = (float4*)d_out;

    const size_t aggFloats = (size_t)NC * Bt * HD4 * 4;   // 2 MiB
    const size_t sgFloats  = (size_t)(NC / 8) * Bt * HD4 * 4;
    float* aggf   = (float*)d_ws;
    float* sgf    = aggf + aggFloats;
    int*   ticket = (int*)(sgf + sgFloats);

    (void)hipMemsetAsync(aggf, 0xFF, (aggFloats + sgFloats) * sizeof(float), stream);
    (void)hipMemsetAsync(ticket, 0, sizeof(int), stream);

    ema_onepass<<<dim3(NBLK), dim3(512), 0, stream>>>(values4, sw, v0f, out4,
                                                      aggf, sgf, ticket);
}

// Round 12
// 62.397 us; speedup vs baseline: 3.2266x; 1.0187x over previous
//
#include <hip/hip_runtime.h>

// Exponential smoothing: s[-1]=v0; s[j] = w*s[j-1] + (1-w)*x[j]; out[j]=s[j]
// w = sigmoid(smoothing_weight[h]).
// Single-pass chained scan; values read ONCE, out written ONCE.
// Round-12 vs round-11 (63.6us, VGPR=60 -> pinned x0/x1 partially SPILLED):
//   - __launch_bounds__(512,3): reg budget ~170 so all 64 data VGPRs + walk
//     scratch fit with zero spill (round-11's (512,4) forced a 64-reg cap)
//   - serial poll-and-fold carry walk (1 outstanding poll) instead of
//     issue-all-then-fixup: walk scratch 16 regs -> ~3 regs at peak
// Layout: 1024 blocks x 512 threads; block=(b, CL=64 chunk); thread owns
// groups g and g+4 (2 x 8 float4 steps in registers, asm-pinned).
// Inter-block comm: relaxed agent atomics + 0xFFFFFFFF sentinel only (no
// fences -> no L2 wb/inv storms). Fixed-order hierarchical walk (<=7 sg +
// <=7 remainder) => bit-deterministic. Ticket keeps dep-order = dispatch
// order => progress regardless of residency.

namespace {

constexpr int Bt   = 16;          // batch
constexpr int Tt   = 4096;        // time
constexpr int HD4  = 128;         // float4 channels per (b,t)
constexpr int CL   = 64;          // chunk length
constexpr int NGRP = 8;           // time-groups per chunk
constexpr int TS   = CL / NGRP;   // 8 steps per group
constexpr int NC   = Tt / CL;     // 64 chunks per batch
constexpr int NBLK = NC * Bt;     // 1024
constexpr int GRPS = 4;           // explicit groups; thread also does g+4
constexpr unsigned SENT = 0xFFFFFFFFu;

typedef float fvec4 __attribute__((ext_vector_type(4)));

__device__ __forceinline__ float sigmoidf_(float x) {
    return 1.0f / (1.0f + expf(-x));
}

__device__ __forceinline__ unsigned ld_relaxed(const unsigned* p) {
    return __hip_atomic_load(p, __ATOMIC_RELAXED, __HIP_MEMORY_SCOPE_AGENT);
}

__device__ __forceinline__ float poll1(const unsigned* p) {
    unsigned u = ld_relaxed(p);
    while (u == SENT) {
        __builtin_amdgcn_s_sleep(2);
        u = ld_relaxed(p);
    }
    return __uint_as_float(u);
}

__device__ __forceinline__ void store1(float* p, float v) {
    __hip_atomic_store(p, v, __ATOMIC_RELAXED, __HIP_MEMORY_SCOPE_AGENT);
}

__device__ __forceinline__ void store4(float* p, const float4& v) {
    store1(p + 0, v.x); store1(p + 1, v.y);
    store1(p + 2, v.z); store1(p + 3, v.w);
}

__global__ __launch_bounds__(512, 3) void ema_onepass(
    const float4* __restrict__ values4, const float* __restrict__ sw,
    const float* __restrict__ v0f, float4* __restrict__ out4,
    float* __restrict__ aggf, float* __restrict__ sgf,
    int* __restrict__ ticket) {

    __shared__ float4 s_A[NGRP][HD4];    // 16 KiB per-group partial aggs
    __shared__ float4 s_Ab[HD4];         // 2 KiB block aggregate
    __shared__ float4 s_carryv[HD4];     // 2 KiB carry
    __shared__ int s_vid;

    const int tid = threadIdx.x;
    if (tid == 0) s_vid = atomicAdd(ticket, 1);
    __syncthreads();
    const int vid = s_vid;
    const int b = vid & (Bt - 1);
    const int c = vid >> 4;              // chunk; deps have lower vid
    const int ch = tid & (HD4 - 1);
    const int g  = tid >> 7;             // 0..3; thread also does group g+4

    const float w   = sigmoidf_(sw[ch >> 4]);
    const float omw = 1.0f - w;
    float W8 = w * w;  W8 = W8 * W8;  W8 = W8 * W8;       // w^8

    // Load 2 x 8 time-steps into registers (groups g and g+4).
    const size_t chunkbase = ((size_t)b * Tt + (size_t)c * CL) * HD4 + ch;
    const float4* p0 = values4 + chunkbase + (size_t)g * TS * HD4;
    const float4* p1 = values4 + chunkbase + (size_t)(g + GRPS) * TS * HD4;
    float4 x0[TS], x1[TS];
    float4 A0 = make_float4(0.f, 0.f, 0.f, 0.f);
    float4 A1 = make_float4(0.f, 0.f, 0.f, 0.f);
    #pragma unroll
    for (int u = 0; u < TS; ++u) {
        x0[u] = p0[(size_t)u * HD4];
        A0.x = fmaf(w, A0.x, omw * x0[u].x);
        A0.y = fmaf(w, A0.y, omw * x0[u].y);
        A0.z = fmaf(w, A0.z, omw * x0[u].z);
        A0.w = fmaf(w, A0.w, omw * x0[u].w);
    }
    #pragma unroll
    for (int u = 0; u < TS; ++u) {
        x1[u] = p1[(size_t)u * HD4];
        A1.x = fmaf(w, A1.x, omw * x1[u].x);
        A1.y = fmaf(w, A1.y, omw * x1[u].y);
        A1.z = fmaf(w, A1.z, omw * x1[u].z);
        A1.w = fmaf(w, A1.w, omw * x1[u].w);
    }
    // Pin the chunk in VGPRs (anti-rematerialization, rounds 5/6 lesson).
    #pragma unroll
    for (int u = 0; u < TS; ++u) {
        asm volatile("" : "+v"(x0[u].x), "+v"(x0[u].y), "+v"(x0[u].z), "+v"(x0[u].w));
        asm volatile("" : "+v"(x1[u].x), "+v"(x1[u].y), "+v"(x1[u].z), "+v"(x1[u].w));
    }
    s_A[g][ch] = A0;
    s_A[g + GRPS][ch] = A1;
    __syncthreads();   // barrier 1

    // Group 3 folds the block aggregate (8 partials) and publishes.
    if (g == 3) {
        float4 t = s_A[0][ch];
        #pragma unroll
        for (int j = 1; j < NGRP; ++j) {
            float4 Aj = s_A[j][ch];
            t.x = fmaf(W8, t.x, Aj.x);
            t.y = fmaf(W8, t.y, Aj.y);
            t.z = fmaf(W8, t.z, Aj.z);
            t.w = fmaf(W8, t.w, Aj.w);
        }
        s_Ab[ch] = t;
        store4(aggf + (((size_t)c * Bt + b) * HD4 + ch) * 4, t);
    }
    __syncthreads();   // barrier 2

    // ---- Carry walk: all 512 threads, one float channel each ----
    // Serial poll-and-fold: only ~3 scratch regs live while x0/x1 pinned.
    const float ws = sigmoidf_(sw[tid >> 6]);
    float Wcs = ws * ws;
    #pragma unroll
    for (int i = 0; i < 5; ++i) Wcs = Wcs * Wcs;           // w^64 = w^CL
    float WSGs = Wcs;
    #pragma unroll
    for (int i = 0; i < 3; ++i) WSGs = WSGs * WSGs;        // w^512

    float sc;
    {
        const unsigned* au = (const unsigned*)aggf;
        const unsigned* su = (const unsigned*)sgf;
        const int mf  = c >> 3;          // complete supergroups (SG=8)
        const int k0  = mf << 3;
        const int rem = c - k0;          // 0..7

        // Phase 1: remainder scan R (seed 0), serial fold.
        float R = 0.0f;
        #pragma unroll
        for (int j = 0; j < 7; ++j) {
            if (k0 + j < c) {
                float av = poll1(au + ((size_t)(k0 + j) * Bt + b) * (HD4 * 4) + tid);
                R = fmaf(Wcs, R, av);
            }
        }

        // Phase 2: supergroup producer publishes immediately (local deps).
        if ((c & 7) == 7) {
            float ab = ((const float*)s_Ab)[tid];
            store1(sgf + ((size_t)mf * Bt + b) * (HD4 * 4) + tid,
                   fmaf(Wcs, R, ab));
            asm volatile("" ::: "memory");
        }

        // Phase 3: supergroup prefix P (seed v0), serial fold.
        float P = v0f[tid];
        #pragma unroll
        for (int j = 0; j < 7; ++j) {
            if (j < mf) {
                float svv = poll1(su + ((size_t)j * Bt + b) * (HD4 * 4) + tid);
                P = fmaf(WSGs, P, svv);
            }
        }

        // carry = Wc^rem * P + R   (rem in 0..7)
        float Wr = 1.0f, pw = Wcs;
        if (rem & 1) Wr *= pw;  pw *= pw;
        if (rem & 2) Wr *= pw;  pw *= pw;
        if (rem & 4) Wr *= pw;
        sc = fmaf(Wr, P, R);
    }
    ((float*)s_carryv)[tid] = sc;
    __syncthreads();   // barrier 3

    // Seeds for my two groups: fold partial aggs of groups < g (and < g+4).
    float4 s0 = s_carryv[ch];
    #pragma unroll
    for (int j = 0; j < NGRP - 1; ++j) {
        if (j < g) {
            float4 Aj = s_A[j][ch];
            s0.x = fmaf(W8, s0.x, Aj.x);
            s0.y = fmaf(W8, s0.y, Aj.y);
            s0.z = fmaf(W8, s0.z, Aj.z);
            s0.w = fmaf(W8, s0.w, Aj.w);
        }
    }
    float4 s1 = s_carryv[ch];
    #pragma unroll
    for (int j = 0; j < NGRP - 1; ++j) {
        if (j < g + GRPS) {
            float4 Aj = s_A[j][ch];
            s1.x = fmaf(W8, s1.x, Aj.x);
            s1.y = fmaf(W8, s1.y, Aj.y);
            s1.z = fmaf(W8, s1.z, Aj.z);
            s1.w = fmaf(W8, s1.w, Aj.w);
        }
    }

    // Final scans from registers; nontemporal stream out.
    fvec4* q0 = (fvec4*)(out4 + chunkbase + (size_t)g * TS * HD4);
    fvec4* q1 = (fvec4*)(out4 + chunkbase + (size_t)(g + GRPS) * TS * HD4);
    #pragma unroll
    for (int u = 0; u < TS; ++u) {
        s0.x = fmaf(w, s0.x, omw * x0[u].x);
        s0.y = fmaf(w, s0.y, omw * x0[u].y);
        s0.z = fmaf(w, s0.z, omw * x0[u].z);
        s0.w = fmaf(w, s0.w, omw * x0[u].w);
        fvec4 sn = {s0.x, s0.y, s0.z, s0.w};
        __builtin_nontemporal_store(sn, q0 + (size_t)u * HD4);
    }
    #pragma unroll
    for (int u = 0; u < TS; ++u) {
        s1.x = fmaf(w, s1.x, omw * x1[u].x);
        s1.y = fmaf(w, s1.y, omw * x1[u].y);
        s1.z = fmaf(w, s1.z, omw * x1[u].z);
        s1.w = fmaf(w, s1.w, omw * x1[u].w);
        fvec4 sn = {s1.x, s1.y, s1.z, s1.w};
        __builtin_nontemporal_store(sn, q1 + (size_t)u * HD4);
    }
}

}  // namespace

extern "C" void kernel_launch(void* const* d_in, const int* in_sizes, int n_in,
                              void* d_out, int out_size, void* d_ws, size_t ws_size,
                              hipStream_t stream) {
    const float4* values4 = (const float4*)d_in[0];  // [16, 4096, 8, 64] f32
    const float*  sw      = (const float*)d_in[1];   // [8, 1]
    const float*  v0f     = (const float*)d_in[2];   // [1, 1, 8, 64] = 512 f32
    float4* out4 = (float4*)d_out;

    const size_t aggFloats = (size_t)NC * Bt * HD4 * 4;        // 2 MiB
    const size_t sgFloats  = (size_t)(NC / 8) * Bt * HD4 * 4;  // 256 KiB
    float* aggf   = (float*)d_ws;
    float* sgf    = aggf + aggFloats;
    int*   ticket = (int*)(sgf + sgFloats);

    (void)hipMemsetAsync(aggf, 0xFF, (aggFloats + sgFloats) * sizeof(float), stream);
    (void)hipMemsetAsync(ticket, 0, sizeof(int), stream);

    ema_onepass<<<dim3(NBLK), dim3(512), 0, stream>>>(values4, sw, v0f, out4,
                                                      aggf, sgf, ticket);
}